// Round 1
// baseline (735.422 us; speedup 1.0000x reference)
//
#include <hip/hip_runtime.h>

#define I_DIM 1025
#define J_DIM 2048
#define K_B 8
#define EPSF 1e-20f

// ---------------- helpers ----------------

template<int NV>
__device__ __forceinline__ void shflReduce(float* v) {
  #pragma unroll
  for (int off = 32; off > 0; off >>= 1) {
    #pragma unroll
    for (int q = 0; q < NV; ++q) v[q] += __shfl_down(v[q], off);
  }
}

__device__ __forceinline__ float2 cmul(float2 a, float2 b) {
  return make_float2(a.x*b.x - a.y*b.y, a.x*b.y + a.y*b.x);
}
__device__ __forceinline__ float2 cadd(float2 a, float2 b) {
  return make_float2(a.x + b.x, a.y + b.y);
}
__device__ __forceinline__ float2 csub(float2 a, float2 b) {
  return make_float2(a.x - b.x, a.y - b.y);
}
__device__ __forceinline__ float2 cdiv(float2 a, float2 b) {
  float s = 1.0f / (b.x*b.x + b.y*b.y);
  return make_float2((a.x*b.x + a.y*b.y)*s, (a.y*b.x - a.x*b.y)*s);
}

// ---------------- init: T/V layout change + W = identity ----------------
// T layout: [n][i][k]   (2 x 1025 x 8)
// V layout: [n][k][j]   (2 x 8 x 2048)
// W layout: [i][n][m][c] (1025 x 8 floats), complex interleaved
__global__ __launch_bounds__(256) void k_init(
    const float* __restrict__ T0, const float* __restrict__ V0,
    float* __restrict__ T, float* __restrict__ V, float* __restrict__ W)
{
  int t = blockIdx.x * 256 + threadIdx.x;
  if (t < 2 * K_B * J_DIM) {               // V: 32768
    int n = t / (K_B * J_DIM);
    int r = t % (K_B * J_DIM);
    int k = r / J_DIM, j = r % J_DIM;
    V[t] = V0[(k * J_DIM + j) * 2 + n];
  }
  if (t < 2 * I_DIM * K_B) {               // T: 16400
    int n = t / (I_DIM * K_B);
    int r = t % (I_DIM * K_B);
    int i = r / K_B, k = r % K_B;
    T[t] = T0[(i * K_B + k) * 2 + n];
  }
  if (t < I_DIM * 8) {                     // W: 8200
    int u = t & 7;
    int c = u & 1, m = (u >> 1) & 1, n = u >> 2;
    W[t] = (n == m && c == 0) ? 1.0f : 0.0f;
  }
}

// ---------------- transpose X (M,J,I,2) -> Xre/Xim [m][i][j] ----------------
__global__ __launch_bounds__(256) void k_transpose(
    const float* __restrict__ X, float* __restrict__ Xre, float* __restrict__ Xim)
{
  __shared__ float tre[32][33];
  __shared__ float tim[32][33];
  const int m = blockIdx.z;
  const int i0 = blockIdx.x * 32, j0 = blockIdx.y * 32;
  const int tx = threadIdx.x, ty = threadIdx.y;  // (32, 8)
  const float2* __restrict__ X2 = (const float2*)X;
  #pragma unroll
  for (int jj = 0; jj < 4; ++jj) {
    int jl = ty + jj * 8;
    int i = i0 + tx;
    if (i < I_DIM) {
      float2 v = X2[(size_t)(m * J_DIM + j0 + jl) * I_DIM + i];
      tre[jl][tx] = v.x;
      tim[jl][tx] = v.y;
    }
  }
  __syncthreads();
  #pragma unroll
  for (int ii = 0; ii < 4; ++ii) {
    int il = ty + ii * 8;
    int i = i0 + il;
    if (i < I_DIM) {
      Xre[(size_t)(m * I_DIM + i) * J_DIM + j0 + tx] = tre[tx][il];
      Xim[(size_t)(m * I_DIM + i) * J_DIM + j0 + tx] = tim[tx][il];
    }
  }
}

// ---------------- NMF T-step (fused: Y-row recompute, YdR store, T update) ----
// one block per frequency i; 256 threads over j
__global__ __launch_bounds__(256) void k_nmfT(
    const float* __restrict__ Xre, const float* __restrict__ Xim,
    float* __restrict__ T, const float* __restrict__ V,
    const float* __restrict__ W, float* __restrict__ YdR, int n)
{
  const int i = blockIdx.x;
  const int tid = threadIdx.x;
  const float4 w = ((const float4*)W)[i * 2 + n];  // W[i][n][0..1] complex
  float t[K_B];
  const int trow = (n * I_DIM + i) * K_B;
  #pragma unroll
  for (int k = 0; k < K_B; ++k) t[k] = T[trow + k];
  const float* __restrict__ Vn = V + n * (K_B * J_DIM);
  const float* __restrict__ xr0 = Xre + (size_t)(0 * I_DIM + i) * J_DIM;
  const float* __restrict__ xi0 = Xim + (size_t)(0 * I_DIM + i) * J_DIM;
  const float* __restrict__ xr1 = Xre + (size_t)(1 * I_DIM + i) * J_DIM;
  const float* __restrict__ xi1 = Xim + (size_t)(1 * I_DIM + i) * J_DIM;

  float num[K_B], den[K_B];
  #pragma unroll
  for (int k = 0; k < K_B; ++k) { num[k] = 0.f; den[k] = 0.f; }

  #pragma unroll
  for (int jj = 0; jj < J_DIM / 256; ++jj) {
    int j = jj * 256 + tid;
    float a0 = xr0[j], b0 = xi0[j], a1 = xr1[j], b1 = xi1[j];
    float yr = w.x * a0 - w.y * b0 + w.z * a1 - w.w * b1;
    float yi = w.x * b0 + w.y * a0 + w.z * b1 + w.w * a1;
    float ym2 = yr * yr + yi * yi;
    float v[K_B];
    float rn = 0.f;
    #pragma unroll
    for (int k = 0; k < K_B; ++k) { v[k] = Vn[k * J_DIM + j]; rn += t[k] * v[k]; }
    float mr = fabsf(rn);
    float ydr = ym2 / (mr * mr + EPSF);
    float rd = 1.0f / (mr + EPSF);
    YdR[(size_t)i * J_DIM + j] = ydr;
    #pragma unroll
    for (int k = 0; k < K_B; ++k) { num[k] += ydr * v[k]; den[k] += rd * v[k]; }
  }

  float vals[16];
  #pragma unroll
  for (int k = 0; k < K_B; ++k) { vals[k] = num[k]; vals[K_B + k] = den[k]; }
  shflReduce<16>(vals);
  __shared__ float red[4][16];
  int wave = tid >> 6, lane = tid & 63;
  if (lane == 0) {
    #pragma unroll
    for (int q = 0; q < 16; ++q) red[wave][q] = vals[q];
  }
  __syncthreads();
  if (tid < K_B) {
    float nm = red[0][tid] + red[1][tid] + red[2][tid] + red[3][tid];
    float dn = red[0][tid + 8] + red[1][tid + 8] + red[2][tid + 8] + red[3][tid + 8];
    float tv = T[trow + tid];
    T[trow + tid] = tv * sqrtf(nm / (dn + EPSF));
  }
}

// ---------------- NMF V-step (fused: Rd2 recompute, V update) ----------------
// 64 blocks; block covers 32 j-columns, 8 i-strided groups of 32 threads
__global__ __launch_bounds__(256) void k_nmfV(
    const float* __restrict__ T, float* __restrict__ V,
    const float* __restrict__ YdR, int n)
{
  __shared__ __align__(16) float sT[I_DIM * K_B];  // 32800 B
  __shared__ float pn[256 * K_B];                  // 8 KB
  __shared__ float pd[256 * K_B];                  // 8 KB
  const int tid = threadIdx.x;
  for (int s = tid; s < I_DIM * K_B; s += 256) sT[s] = T[n * I_DIM * K_B + s];
  __syncthreads();
  const int jl = tid & 31, ig = tid >> 5;
  const int j = blockIdx.x * 32 + jl;
  float* __restrict__ Vn = V + n * (K_B * J_DIM);
  float v[K_B];
  #pragma unroll
  for (int k = 0; k < K_B; ++k) v[k] = Vn[k * J_DIM + j];
  float num[K_B], den[K_B];
  #pragma unroll
  for (int k = 0; k < K_B; ++k) { num[k] = 0.f; den[k] = 0.f; }

  for (int i = ig; i < I_DIM; i += 8) {
    const float4* t4 = (const float4*)(sT + i * K_B);
    float4 ta = t4[0], tb = t4[1];
    float tk[K_B] = {ta.x, ta.y, ta.z, ta.w, tb.x, tb.y, tb.z, tb.w};
    float ydr = YdR[(size_t)i * J_DIM + j];
    float rn = 0.f;
    #pragma unroll
    for (int k = 0; k < K_B; ++k) rn += tk[k] * v[k];
    float rd2 = 1.0f / (fabsf(rn) + EPSF);
    #pragma unroll
    for (int k = 0; k < K_B; ++k) { num[k] += tk[k] * ydr; den[k] += tk[k] * rd2; }
  }
  #pragma unroll
  for (int k = 0; k < K_B; ++k) { pn[tid * K_B + k] = num[k]; pd[tid * K_B + k] = den[k]; }
  __syncthreads();
  // 256 outputs: (k_out = tid>>5, j_out = tid&31)
  const int ko = tid >> 5, jo = tid & 31;
  float nm = 0.f, dn = 0.f;
  #pragma unroll
  for (int g = 0; g < 8; ++g) {
    int src = (g * 32 + jo) * K_B + ko;
    nm += pn[src];
    dn += pd[src];
  }
  const int jout = blockIdx.x * 32 + jo;
  Vn[ko * J_DIM + jout] *= sqrtf(nm / (dn + EPSF));
}

// ---------------- IP step (fused: D covariance, 2x2 solve, W row update) -----
// one block per frequency i
__global__ __launch_bounds__(256) void k_ip(
    const float* __restrict__ Xre, const float* __restrict__ Xim,
    const float* __restrict__ T, const float* __restrict__ V,
    float* __restrict__ W, int n)
{
  const int i = blockIdx.x;
  const int tid = threadIdx.x;
  float t[K_B];
  const int trow = (n * I_DIM + i) * K_B;
  #pragma unroll
  for (int k = 0; k < K_B; ++k) t[k] = T[trow + k];
  const float* __restrict__ Vn = V + n * (K_B * J_DIM);
  const float* __restrict__ xr0 = Xre + (size_t)(0 * I_DIM + i) * J_DIM;
  const float* __restrict__ xi0 = Xim + (size_t)(0 * I_DIM + i) * J_DIM;
  const float* __restrict__ xr1 = Xre + (size_t)(1 * I_DIM + i) * J_DIM;
  const float* __restrict__ xi1 = Xim + (size_t)(1 * I_DIM + i) * J_DIM;

  float d00 = 0.f, d01r = 0.f, d01i = 0.f, d11 = 0.f;
  #pragma unroll
  for (int jj = 0; jj < J_DIM / 256; ++jj) {
    int j = jj * 256 + tid;
    float rn = 0.f;
    #pragma unroll
    for (int k = 0; k < K_B; ++k) rn += t[k] * Vn[k * J_DIM + j];
    float wgt = 1.0f / (rn + EPSF);   // reference: 1/(Rn + IP_EPS), no abs
    float a0 = xr0[j], b0 = xi0[j], a1 = xr1[j], b1 = xi1[j];
    d00 += (a0 * a0 + b0 * b0) * wgt;
    d11 += (a1 * a1 + b1 * b1) * wgt;
    d01r += (a0 * a1 + b0 * b1) * wgt;
    d01i += (b0 * a1 - a0 * b1) * wgt;
  }
  float vals[4] = {d00, d01r, d01i, d11};
  shflReduce<4>(vals);
  __shared__ float red[4][4];
  int wave = tid >> 6, lane = tid & 63;
  if (lane == 0) {
    #pragma unroll
    for (int q = 0; q < 4; ++q) red[wave][q] = vals[q];
  }
  __syncthreads();
  if (tid == 0) {
    const float invJ = 1.0f / (float)J_DIM;
    float D00 = (red[0][0] + red[1][0] + red[2][0] + red[3][0]) * invJ + EPSF;
    float p   = (red[0][1] + red[1][1] + red[2][1] + red[3][1]) * invJ;
    float q   = (red[0][2] + red[1][2] + red[2][2] + red[3][2]) * invJ;
    float D11 = (red[0][3] + red[1][3] + red[2][3] + red[3][3]) * invJ + EPSF;
    float2 D01 = make_float2(p, q);
    float2 D10 = make_float2(p, -q);
    float4 w0 = ((const float4*)W)[i * 2 + 0];
    float4 w1 = ((const float4*)W)[i * 2 + 1];
    float2 W00 = make_float2(w0.x, w0.y), W01 = make_float2(w0.z, w0.w);
    float2 W10 = make_float2(w1.x, w1.y), W11 = make_float2(w1.z, w1.w);
    // A = W @ Dreg
    float2 A00 = cadd(make_float2(W00.x * D00, W00.y * D00), cmul(W01, D10));
    float2 A01 = cadd(cmul(W00, D01), make_float2(W01.x * D11, W01.y * D11));
    float2 A10 = cadd(make_float2(W10.x * D00, W10.y * D00), cmul(W11, D10));
    float2 A11 = cadd(cmul(W10, D01), make_float2(W11.x * D11, W11.y * D11));
    float2 det = csub(cmul(A00, A11), cmul(A01, A10));
    float2 b0, b1;
    if (n == 0) {
      b0 = cdiv(A11, det);
      b1 = cdiv(make_float2(-A10.x, -A10.y), det);
    } else {
      b0 = cdiv(make_float2(-A01.x, -A01.y), det);
      b1 = cdiv(A00, det);
    }
    // Db = Dreg @ b
    float2 Db0 = cadd(make_float2(D00 * b0.x, D00 * b0.y), cmul(D01, b1));
    float2 Db1 = cadd(cmul(D10, b0), make_float2(D11 * b1.x, D11 * b1.y));
    float ip = b0.x * Db0.x + b0.y * Db0.y + b1.x * Db1.x + b1.y * Db1.y;
    float inv = 1.0f / sqrtf(ip + EPSF);
    ((float4*)W)[i * 2 + n] = make_float4(b0.x * inv, -b0.y * inv, b1.x * inv, -b1.y * inv);
  }
}

// ---------------- output: Y = W @ Xc, layout (N, J, I, 2) --------------------
__global__ __launch_bounds__(256) void k_out(
    const float* __restrict__ X, const float* __restrict__ W, float* __restrict__ out)
{
  const int j = blockIdx.x;
  const int i = blockIdx.y * 256 + threadIdx.x;
  if (i >= I_DIM) return;
  const float2* __restrict__ X2 = (const float2*)X;
  float2 x0 = X2[(size_t)(0 * J_DIM + j) * I_DIM + i];
  float2 x1 = X2[(size_t)(1 * J_DIM + j) * I_DIM + i];
  const float4* __restrict__ W4 = (const float4*)W;
  float4 w0 = W4[i * 2 + 0];
  float4 w1 = W4[i * 2 + 1];
  float2* __restrict__ O = (float2*)out;
  float yr = w0.x * x0.x - w0.y * x0.y + w0.z * x1.x - w0.w * x1.y;
  float yi = w0.x * x0.y + w0.y * x0.x + w0.z * x1.y + w0.w * x1.x;
  O[(size_t)(0 * J_DIM + j) * I_DIM + i] = make_float2(yr, yi);
  yr = w1.x * x0.x - w1.y * x0.y + w1.z * x1.x - w1.w * x1.y;
  yi = w1.x * x0.y + w1.y * x0.x + w1.z * x1.y + w1.w * x1.x;
  O[(size_t)(1 * J_DIM + j) * I_DIM + i] = make_float2(yr, yi);
}

// ---------------- launch ----------------
extern "C" void kernel_launch(void* const* d_in, const int* in_sizes, int n_in,
                              void* d_out, int out_size, void* d_ws, size_t ws_size,
                              hipStream_t stream) {
  const float* X  = (const float*)d_in[0];   // (2, 2048, 1025, 2)
  const float* T0 = (const float*)d_in[1];   // (1025, 8, 2)
  const float* V0 = (const float*)d_in[2];   // (8, 2048, 2)
  float* ws = (float*)d_ws;
  // workspace layout (floats)
  float* Xre = ws;                    // 2*1025*2048 = 4198400
  float* Xim = ws + 4198400;          // 4198400
  float* YdR = ws + 8396800;          // 1025*2048  = 2099200
  float* T   = ws + 10496000;         // 2*1025*8   = 16400
  float* V   = ws + 10512400;         // 2*8*2048   = 32768
  float* W   = ws + 10545168;         // 1025*8     = 8200   (16B-aligned)
  float* out = (float*)d_out;

  k_init<<<128, 256, 0, stream>>>(T0, V0, T, V, W);
  k_transpose<<<dim3(33, 64, 2), dim3(32, 8), 0, stream>>>(X, Xre, Xim);
  for (int it = 0; it < 5; ++it) {
    for (int n = 0; n < 2; ++n) {
      k_nmfT<<<I_DIM, 256, 0, stream>>>(Xre, Xim, T, V, W, YdR, n);
      k_nmfV<<<64, 256, 0, stream>>>(T, V, YdR, n);
      k_ip<<<I_DIM, 256, 0, stream>>>(Xre, Xim, T, V, W, n);
    }
  }
  k_out<<<dim3(J_DIM, 5), 256, 0, stream>>>(X, W, out);
}

// Round 2
// 424.506 us; speedup vs baseline: 1.7324x; 1.7324x over previous
//
#include <hip/hip_runtime.h>

#define I_DIM 1025
#define J_DIM 2048
#define K_B 8
#define IC 33            // i-chunks of 32 (last chunk has 1)
#define EPSF 1e-20f

// ---------------- helpers ----------------

template<int NV>
__device__ __forceinline__ void shflReduce(float* v) {
  #pragma unroll
  for (int off = 32; off > 0; off >>= 1) {
    #pragma unroll
    for (int q = 0; q < NV; ++q) v[q] += __shfl_down(v[q], off);
  }
}

__device__ __forceinline__ float2 cmul(float2 a, float2 b) {
  return make_float2(a.x*b.x - a.y*b.y, a.x*b.y + a.y*b.x);
}
__device__ __forceinline__ float2 cadd(float2 a, float2 b) {
  return make_float2(a.x + b.x, a.y + b.y);
}
__device__ __forceinline__ float2 csub(float2 a, float2 b) {
  return make_float2(a.x - b.x, a.y - b.y);
}
__device__ __forceinline__ float2 cdiv(float2 a, float2 b) {
  float s = 1.0f / (b.x*b.x + b.y*b.y);
  return make_float2((a.x*b.x + a.y*b.y)*s, (a.y*b.x - a.x*b.y)*s);
}

// ---------------- init: T/V layout change + W = identity ----------------
// T layout: [n][i][k]   (2 x 1025 x 8)
// V layout: [n][k][j]   (2 x 8 x 2048)
// W layout: [i][n][m][c] (1025 x 8 floats), complex interleaved
__global__ __launch_bounds__(256) void k_init(
    const float* __restrict__ T0, const float* __restrict__ V0,
    float* __restrict__ T, float* __restrict__ V, float* __restrict__ W)
{
  int t = blockIdx.x * 256 + threadIdx.x;
  if (t < 2 * K_B * J_DIM) {               // V: 32768
    int n = t / (K_B * J_DIM);
    int r = t % (K_B * J_DIM);
    int k = r / J_DIM, j = r % J_DIM;
    V[t] = V0[(k * J_DIM + j) * 2 + n];
  }
  if (t < 2 * I_DIM * K_B) {               // T: 16400
    int n = t / (I_DIM * K_B);
    int r = t % (I_DIM * K_B);
    int i = r / K_B, k = r % K_B;
    T[t] = T0[(i * K_B + k) * 2 + n];
  }
  if (t < I_DIM * 8) {                     // W: 8200
    int u = t & 7;
    int c = u & 1, m = (u >> 1) & 1, n = u >> 2;
    W[t] = (n == m && c == 0) ? 1.0f : 0.0f;
  }
}

// ---------------- transpose X (M,J,I,2) -> Xre/Xim [m][i][j] ----------------
__global__ __launch_bounds__(256) void k_transpose(
    const float* __restrict__ X, float* __restrict__ Xre, float* __restrict__ Xim)
{
  __shared__ float tre[32][33];
  __shared__ float tim[32][33];
  const int m = blockIdx.z;
  const int i0 = blockIdx.x * 32, j0 = blockIdx.y * 32;
  const int tx = threadIdx.x, ty = threadIdx.y;  // (32, 8)
  const float2* __restrict__ X2 = (const float2*)X;
  #pragma unroll
  for (int jj = 0; jj < 4; ++jj) {
    int jl = ty + jj * 8;
    int i = i0 + tx;
    if (i < I_DIM) {
      float2 v = X2[(size_t)(m * J_DIM + j0 + jl) * I_DIM + i];
      tre[jl][tx] = v.x;
      tim[jl][tx] = v.y;
    }
  }
  __syncthreads();
  #pragma unroll
  for (int ii = 0; ii < 4; ++ii) {
    int il = ty + ii * 8;
    int i = i0 + il;
    if (i < I_DIM) {
      Xre[(size_t)(m * I_DIM + i) * J_DIM + j0 + tx] = tre[tx][il];
      Xim[(size_t)(m * I_DIM + i) * J_DIM + j0 + tx] = tim[tx][il];
    }
  }
}

// ---------------- NMF T-step body (Y-row recompute, YdR store, T update) -----
__device__ __forceinline__ void nmfT_body(
    int i, int tid,
    const float* __restrict__ Xre, const float* __restrict__ Xim,
    float* __restrict__ T, const float* __restrict__ V,
    const float* __restrict__ W, float* __restrict__ YdR, int n)
{
  const float4 w = ((const float4*)W)[i * 2 + n];  // W[i][n][0..1] complex
  float t[K_B];
  const int trow = (n * I_DIM + i) * K_B;
  #pragma unroll
  for (int k = 0; k < K_B; ++k) t[k] = T[trow + k];
  const float* __restrict__ Vn = V + n * (K_B * J_DIM);
  const float* __restrict__ xr0 = Xre + (size_t)(0 * I_DIM + i) * J_DIM;
  const float* __restrict__ xi0 = Xim + (size_t)(0 * I_DIM + i) * J_DIM;
  const float* __restrict__ xr1 = Xre + (size_t)(1 * I_DIM + i) * J_DIM;
  const float* __restrict__ xi1 = Xim + (size_t)(1 * I_DIM + i) * J_DIM;

  float num[K_B], den[K_B];
  #pragma unroll
  for (int k = 0; k < K_B; ++k) { num[k] = 0.f; den[k] = 0.f; }

  #pragma unroll
  for (int jj = 0; jj < J_DIM / 256; ++jj) {
    int j = jj * 256 + tid;
    float a0 = xr0[j], b0 = xi0[j], a1 = xr1[j], b1 = xi1[j];
    float yr = w.x * a0 - w.y * b0 + w.z * a1 - w.w * b1;
    float yi = w.x * b0 + w.y * a0 + w.z * b1 + w.w * a1;
    float ym2 = yr * yr + yi * yi;
    float v[K_B];
    float rn = 0.f;
    #pragma unroll
    for (int k = 0; k < K_B; ++k) { v[k] = Vn[k * J_DIM + j]; rn += t[k] * v[k]; }
    float mr = fabsf(rn);
    float ydr = ym2 / (mr * mr + EPSF);
    float rd = 1.0f / (mr + EPSF);
    YdR[(size_t)i * J_DIM + j] = ydr;
    #pragma unroll
    for (int k = 0; k < K_B; ++k) { num[k] += ydr * v[k]; den[k] += rd * v[k]; }
  }

  float vals[16];
  #pragma unroll
  for (int k = 0; k < K_B; ++k) { vals[k] = num[k]; vals[K_B + k] = den[k]; }
  shflReduce<16>(vals);
  __shared__ float redT[4][16];
  int wave = tid >> 6, lane = tid & 63;
  if (lane == 0) {
    #pragma unroll
    for (int q = 0; q < 16; ++q) redT[wave][q] = vals[q];
  }
  __syncthreads();
  if (tid < K_B) {
    float nm = redT[0][tid] + redT[1][tid] + redT[2][tid] + redT[3][tid];
    float dn = redT[0][tid + 8] + redT[1][tid + 8] + redT[2][tid + 8] + redT[3][tid + 8];
    float tv = T[trow + tid];
    T[trow + tid] = tv * sqrtf(nm / (dn + EPSF));
  }
}

// ---------------- IP step body (D covariance, 2x2 solve, W row update) -------
__device__ __forceinline__ void ip_body(
    int i, int tid,
    const float* __restrict__ Xre, const float* __restrict__ Xim,
    const float* __restrict__ T, const float* __restrict__ V,
    float* __restrict__ W, int n)
{
  float t[K_B];
  const int trow = (n * I_DIM + i) * K_B;
  #pragma unroll
  for (int k = 0; k < K_B; ++k) t[k] = T[trow + k];
  const float* __restrict__ Vn = V + n * (K_B * J_DIM);
  const float* __restrict__ xr0 = Xre + (size_t)(0 * I_DIM + i) * J_DIM;
  const float* __restrict__ xi0 = Xim + (size_t)(0 * I_DIM + i) * J_DIM;
  const float* __restrict__ xr1 = Xre + (size_t)(1 * I_DIM + i) * J_DIM;
  const float* __restrict__ xi1 = Xim + (size_t)(1 * I_DIM + i) * J_DIM;

  float d00 = 0.f, d01r = 0.f, d01i = 0.f, d11 = 0.f;
  #pragma unroll
  for (int jj = 0; jj < J_DIM / 256; ++jj) {
    int j = jj * 256 + tid;
    float rn = 0.f;
    #pragma unroll
    for (int k = 0; k < K_B; ++k) rn += t[k] * Vn[k * J_DIM + j];
    float wgt = 1.0f / (rn + EPSF);   // reference: 1/(Rn + IP_EPS), no abs
    float a0 = xr0[j], b0 = xi0[j], a1 = xr1[j], b1 = xi1[j];
    d00 += (a0 * a0 + b0 * b0) * wgt;
    d11 += (a1 * a1 + b1 * b1) * wgt;
    d01r += (a0 * a1 + b0 * b1) * wgt;
    d01i += (b0 * a1 - a0 * b1) * wgt;
  }
  float vals[4] = {d00, d01r, d01i, d11};
  shflReduce<4>(vals);
  __shared__ float redI[4][4];
  int wave = tid >> 6, lane = tid & 63;
  if (lane == 0) {
    #pragma unroll
    for (int q = 0; q < 4; ++q) redI[wave][q] = vals[q];
  }
  __syncthreads();
  if (tid == 0) {
    const float invJ = 1.0f / (float)J_DIM;
    float D00 = (redI[0][0] + redI[1][0] + redI[2][0] + redI[3][0]) * invJ + EPSF;
    float p   = (redI[0][1] + redI[1][1] + redI[2][1] + redI[3][1]) * invJ;
    float q   = (redI[0][2] + redI[1][2] + redI[2][2] + redI[3][2]) * invJ;
    float D11 = (redI[0][3] + redI[1][3] + redI[2][3] + redI[3][3]) * invJ + EPSF;
    float2 D01 = make_float2(p, q);
    float2 D10 = make_float2(p, -q);
    float4 w0 = ((const float4*)W)[i * 2 + 0];
    float4 w1 = ((const float4*)W)[i * 2 + 1];
    float2 W00 = make_float2(w0.x, w0.y), W01 = make_float2(w0.z, w0.w);
    float2 W10 = make_float2(w1.x, w1.y), W11 = make_float2(w1.z, w1.w);
    // A = W @ Dreg
    float2 A00 = cadd(make_float2(W00.x * D00, W00.y * D00), cmul(W01, D10));
    float2 A01 = cadd(cmul(W00, D01), make_float2(W01.x * D11, W01.y * D11));
    float2 A10 = cadd(make_float2(W10.x * D00, W10.y * D00), cmul(W11, D10));
    float2 A11 = cadd(cmul(W10, D01), make_float2(W11.x * D11, W11.y * D11));
    float2 det = csub(cmul(A00, A11), cmul(A01, A10));
    float2 b0, b1;
    if (n == 0) {
      b0 = cdiv(A11, det);
      b1 = cdiv(make_float2(-A10.x, -A10.y), det);
    } else {
      b0 = cdiv(make_float2(-A01.x, -A01.y), det);
      b1 = cdiv(A00, det);
    }
    // Db = Dreg @ b
    float2 Db0 = cadd(make_float2(D00 * b0.x, D00 * b0.y), cmul(D01, b1));
    float2 Db1 = cadd(cmul(D10, b0), make_float2(D11 * b1.x, D11 * b1.y));
    float ip = b0.x * Db0.x + b0.y * Db0.y + b1.x * Db1.x + b1.y * Db1.y;
    float inv = 1.0f / sqrtf(ip + EPSF);
    ((float4*)W)[i * 2 + n] = make_float4(b0.x * inv, -b0.y * inv, b1.x * inv, -b1.y * inv);
  }
}

// ---------------- standalone wrappers ----------------
__global__ __launch_bounds__(256) void k_nmfT(
    const float* __restrict__ Xre, const float* __restrict__ Xim,
    float* __restrict__ T, const float* __restrict__ V,
    const float* __restrict__ W, float* __restrict__ YdR, int n)
{
  nmfT_body(blockIdx.x, threadIdx.x, Xre, Xim, T, V, W, YdR, n);
}

__global__ __launch_bounds__(256) void k_ip(
    const float* __restrict__ Xre, const float* __restrict__ Xim,
    const float* __restrict__ T, const float* __restrict__ V,
    float* __restrict__ W, int n)
{
  ip_body(blockIdx.x, threadIdx.x, Xre, Xim, T, V, W, n);
}

// fused: ip(n_ip) on blocks [0,1025), nmfT(n_t) on blocks [1025,2050)
__global__ __launch_bounds__(256) void k_fused(
    const float* __restrict__ Xre, const float* __restrict__ Xim,
    float* __restrict__ T, const float* __restrict__ V,
    float* __restrict__ W, float* __restrict__ YdR, int n_ip, int n_t)
{
  if (blockIdx.x < I_DIM)
    ip_body(blockIdx.x, threadIdx.x, Xre, Xim, T, V, W, n_ip);
  else
    nmfT_body(blockIdx.x - I_DIM, threadIdx.x, Xre, Xim, T, V, W, YdR, n_t);
}

// ---------------- NMF V-step, phase A: partial sums --------------------------
// grid: 8 j-blocks x 33 i-chunks = 264 blocks; thread owns one j column
__global__ __launch_bounds__(256) void k_nmfVpart(
    const float* __restrict__ T, const float* __restrict__ V,
    const float* __restrict__ YdR,
    float* __restrict__ Pn, float* __restrict__ Pd, int n)
{
  const int tid = threadIdx.x;
  const int jb = blockIdx.x & 7;
  const int c  = blockIdx.x >> 3;
  const int j  = jb * 256 + tid;
  const int i0 = c * 32;
  const int ni = min(32, I_DIM - i0);
  __shared__ float sT[32][K_B];
  if (tid < ni * K_B) sT[tid >> 3][tid & 7] = T[(n * I_DIM + i0) * K_B + tid];
  __syncthreads();
  const float* __restrict__ Vn = V + n * (K_B * J_DIM);
  float v[K_B];
  #pragma unroll
  for (int k = 0; k < K_B; ++k) v[k] = Vn[k * J_DIM + j];
  float num[K_B], den[K_B];
  #pragma unroll
  for (int k = 0; k < K_B; ++k) { num[k] = 0.f; den[k] = 0.f; }
  for (int ii = 0; ii < ni; ++ii) {
    float ydr = YdR[(size_t)(i0 + ii) * J_DIM + j];
    float rn = 0.f;
    #pragma unroll
    for (int k = 0; k < K_B; ++k) rn += sT[ii][k] * v[k];   // broadcast reads
    float rd2 = 1.0f / (fabsf(rn) + EPSF);
    #pragma unroll
    for (int k = 0; k < K_B; ++k) { num[k] += sT[ii][k] * ydr; den[k] += sT[ii][k] * rd2; }
  }
  #pragma unroll
  for (int k = 0; k < K_B; ++k) {
    Pn[((size_t)c * K_B + k) * J_DIM + j] = num[k];
    Pd[((size_t)c * K_B + k) * J_DIM + j] = den[k];
  }
}

// ---------------- NMF V-step, phase B: finalize ------------------------------
__global__ __launch_bounds__(256) void k_nmfVfin(
    float* __restrict__ V, const float* __restrict__ Pn,
    const float* __restrict__ Pd, int n)
{
  const int t = blockIdx.x * 256 + threadIdx.x;   // k*2048+j, 16384 total
  float nm = 0.f, dn = 0.f;
  #pragma unroll 11
  for (int c = 0; c < IC; ++c) {
    nm += Pn[(size_t)c * (K_B * J_DIM) + t];
    dn += Pd[(size_t)c * (K_B * J_DIM) + t];
  }
  V[n * (K_B * J_DIM) + t] *= sqrtf(nm / (dn + EPSF));
}

// ---------------- output: Y = W @ Xc, layout (N, J, I, 2) --------------------
__global__ __launch_bounds__(256) void k_out(
    const float* __restrict__ X, const float* __restrict__ W, float* __restrict__ out)
{
  const int j = blockIdx.x;
  const int i = blockIdx.y * 256 + threadIdx.x;
  if (i >= I_DIM) return;
  const float2* __restrict__ X2 = (const float2*)X;
  float2 x0 = X2[(size_t)(0 * J_DIM + j) * I_DIM + i];
  float2 x1 = X2[(size_t)(1 * J_DIM + j) * I_DIM + i];
  const float4* __restrict__ W4 = (const float4*)W;
  float4 w0 = W4[i * 2 + 0];
  float4 w1 = W4[i * 2 + 1];
  float2* __restrict__ O = (float2*)out;
  float yr = w0.x * x0.x - w0.y * x0.y + w0.z * x1.x - w0.w * x1.y;
  float yi = w0.x * x0.y + w0.y * x0.x + w0.z * x1.y + w0.w * x1.x;
  O[(size_t)(0 * J_DIM + j) * I_DIM + i] = make_float2(yr, yi);
  yr = w1.x * x0.x - w1.y * x0.y + w1.z * x1.x - w1.w * x1.y;
  yi = w1.x * x0.y + w1.y * x0.x + w1.z * x1.y + w1.w * x1.x;
  O[(size_t)(1 * J_DIM + j) * I_DIM + i] = make_float2(yr, yi);
}

// ---------------- launch ----------------
extern "C" void kernel_launch(void* const* d_in, const int* in_sizes, int n_in,
                              void* d_out, int out_size, void* d_ws, size_t ws_size,
                              hipStream_t stream) {
  const float* X  = (const float*)d_in[0];   // (2, 2048, 1025, 2)
  const float* T0 = (const float*)d_in[1];   // (1025, 8, 2)
  const float* V0 = (const float*)d_in[2];   // (8, 2048, 2)
  float* ws = (float*)d_ws;
  // workspace layout (floats)
  float* Xre = ws;                    // 4198400
  float* Xim = ws + 4198400;          // 4198400
  float* YdR = ws + 8396800;          // 2099200
  float* T   = ws + 10496000;         // 16400
  float* V   = ws + 10512400;         // 32768
  float* W   = ws + 10545168;         // 8200
  float* Pn  = ws + 10553368;         // 33*8*2048 = 540672
  float* Pd  = ws + 11094040;         // 540672
  float* out = (float*)d_out;

  k_init<<<128, 256, 0, stream>>>(T0, V0, T, V, W);
  k_transpose<<<dim3(33, 64, 2), dim3(32, 8), 0, stream>>>(X, Xre, Xim);
  k_nmfT<<<I_DIM, 256, 0, stream>>>(Xre, Xim, T, V, W, YdR, 0);
  for (int it = 0; it < 5; ++it) {
    // --- source n=0: V update, then ip(0) fused with nmfT(1) ---
    k_nmfVpart<<<8 * IC, 256, 0, stream>>>(T, V, YdR, Pn, Pd, 0);
    k_nmfVfin<<<64, 256, 0, stream>>>(V, Pn, Pd, 0);
    k_fused<<<2 * I_DIM, 256, 0, stream>>>(Xre, Xim, T, V, W, YdR, 0, 1);
    // --- source n=1: V update, then ip(1) fused with next iter's nmfT(0) ---
    k_nmfVpart<<<8 * IC, 256, 0, stream>>>(T, V, YdR, Pn, Pd, 1);
    k_nmfVfin<<<64, 256, 0, stream>>>(V, Pn, Pd, 1);
    if (it < 4) {
      k_fused<<<2 * I_DIM, 256, 0, stream>>>(Xre, Xim, T, V, W, YdR, 1, 0);
    } else {
      k_ip<<<I_DIM, 256, 0, stream>>>(Xre, Xim, T, V, W, 1);
    }
  }
  k_out<<<dim3(J_DIM, 5), 256, 0, stream>>>(X, W, out);
}